// Round 1
// baseline (1266.536 us; speedup 1.0000x reference)
//
#include <hip/hip_runtime.h>
#include <cstdint>
#include <cstddef>

// ---------------- problem constants ----------------
#define BATCH  16
#define DIMK   512
#define LEN    4096        // frames T == L
#define NFFT   1024
#define HOPS   256
#define PADT   384         // (WIN-HOP)/2
#define OUTL   1048576     // per-batch output length = L*HOP
#define KP2    1056        // GEMM2 K: 528 complex bins interleaved (513 used + pad)
#define KP2U   528         // uint32 words per S row

typedef __attribute__((ext_vector_type(8))) short  short8;
typedef __attribute__((ext_vector_type(4))) float  f32x4;

__device__ __forceinline__ unsigned short f2bf(float f) {
    unsigned u = __float_as_uint(f);
    u += 0x7FFFu + ((u >> 16) & 1u);     // RNE
    return (unsigned short)(u >> 16);
}

// ---------------- pack W (gather mag/phase rows pairwise into M-tiles) -------
// Wb row r (r = 128*i + j): j<64 -> W[64i+j] (mag bin 64i+j), j>=64 -> W[1024+64i+j-64]
__global__ void pack_W(const float* __restrict__ W, const float* __restrict__ bvec,
                       unsigned short* __restrict__ Wb, float* __restrict__ bp) {
    const int r = blockIdx.x;               // 0..1151
    const int i = r >> 7, j = r & 127;
    const int src = (j < 64) ? (i * 64 + j) : (1024 + i * 64 + (j - 64));
    for (int c = threadIdx.x; c < DIMK; c += 256)
        Wb[r * DIMK + c] = f2bf(W[src * DIMK + c]);
    if (threadIdx.x == 0) bp[r] = bvec[src];
}

// ---------------- transpose x (B,512,L) f32 -> xT (B,L,512) bf16 -------------
__global__ void transpose_x(const float* __restrict__ x, unsigned short* __restrict__ xT) {
    __shared__ float tile[32][33];
    const int b = blockIdx.z;
    const int l0 = blockIdx.x * 32, d0 = blockIdx.y * 32;
    const int tx = threadIdx.x, ty = threadIdx.y;        // 32 x 8
#pragma unroll
    for (int i = 0; i < 4; ++i)
        tile[ty + 8 * i][tx] = x[((size_t)b * DIMK + d0 + ty + 8 * i) * LEN + l0 + tx];
    __syncthreads();
#pragma unroll
    for (int i = 0; i < 4; ++i)
        xT[((size_t)b * LEN + l0 + ty + 8 * i) * DIMK + d0 + tx] = f2bf(tile[tx][ty + 8 * i]);
}

// ---------------- build D: irfft + hann window as a 1024 x 1056 bf16 matrix --
// frames[n] = w[n]/1024 * [ Re0 + (-1)^n Re512 + sum_{k=1}^{511} 2(Rek cos - Imk sin) ]
__global__ void build_D(unsigned short* __restrict__ D) {
    const int idx = blockIdx.x * 256 + threadIdx.x;
    if (idx >= NFFT * KP2) return;
    const int n = idx / KP2;
    const int j = idx - n * KP2;
    const int k = j >> 1;
    const float wv = 0.5f - 0.5f * __cosf((float)n * (6.283185307179586f / 1024.f));
    float v = 0.f;
    if ((j & 1) == 0) {                                   // Re coefficient
        if (k == 0)        v = wv * (1.f / 1024.f);
        else if (k < 512) {
            const int p = (k * n) & 1023;
            v = 2.f * __cosf((float)p * (6.283185307179586f / 1024.f)) * wv * (1.f / 1024.f);
        } else if (k == 512) v = ((n & 1) ? -wv : wv) * (1.f / 1024.f);
    } else {                                              // Im coefficient
        if (k >= 1 && k < 512) {
            const int p = (k * n) & 1023;
            v = -2.f * __sinf((float)p * (6.283185307179586f / 1024.f)) * wv * (1.f / 1024.f);
        }
    }
    D[idx] = f2bf(v);
}

// ---------------- shared bf16 MFMA GEMM, 128x128 tile, 4 waves ----------------
// A: (Mtiles*128, KDIM) bf16 row-major.  B: per batch rows (bz*LEN+l)*KDIM bf16.
// EPI=1: h -> exp/clip * (cos,sin) -> S complex-interleaved bf16 (uint32 per bin)
// EPI=2: windowed frames -> overlap-add atomicAdd into y
template <int KDIM, int EPI>
__global__ __launch_bounds__(256)
void gemm_kernel(const unsigned short* __restrict__ A,
                 const unsigned short* __restrict__ Bm,
                 const float* __restrict__ bp,
                 unsigned* __restrict__ Sout,
                 float* __restrict__ yout)
{
    __shared__ alignas(16) unsigned short Alds[128 * 40];   // +8 pad: 2-way banks only
    __shared__ alignas(16) unsigned short Blds[128 * 40];

    const int tid  = threadIdx.x;
    const int lane = tid & 63, wv = tid >> 6;
    const int quad = lane >> 4, ln = lane & 15;
    const int bx = blockIdx.x, by = blockIdx.y, bz = blockIdx.z;
    const int m0 = by * 128, l0 = bx * 128;

    const int rA0 = tid >> 1,          kA0 = (tid & 1) * 8;          // not used; see below
    (void)rA0; (void)kA0;
    // 512 16B-chunks per tile: chunk c -> row c>>2, kchunk (c&3)*8
    const int c0 = tid, c1 = tid + 256;
    const int r0 = c0 >> 2, kc0 = (c0 & 3) * 8;
    const int r1 = c1 >> 2, kc1 = (c1 & 3) * 8;

    const size_t bbase = (size_t)bz * LEN * KDIM;

    f32x4 acc[8][2];
#pragma unroll
    for (int a = 0; a < 8; ++a)
#pragma unroll
        for (int c = 0; c < 2; ++c) acc[a][c] = (f32x4){0.f, 0.f, 0.f, 0.f};

    for (int k0 = 0; k0 < KDIM; k0 += 32) {
        *(uint4*)&Alds[r0 * 40 + kc0] = *(const uint4*)&A[(size_t)(m0 + r0) * KDIM + k0 + kc0];
        *(uint4*)&Alds[r1 * 40 + kc1] = *(const uint4*)&A[(size_t)(m0 + r1) * KDIM + k0 + kc1];
        *(uint4*)&Blds[r0 * 40 + kc0] = *(const uint4*)&Bm[bbase + (size_t)(l0 + r0) * KDIM + k0 + kc0];
        *(uint4*)&Blds[r1 * 40 + kc1] = *(const uint4*)&Bm[bbase + (size_t)(l0 + r1) * KDIM + k0 + kc1];
        __syncthreads();

        short8 af[8], bf[2];
#pragma unroll
        for (int rt = 0; rt < 8; ++rt)
            af[rt] = *(const short8*)&Alds[(16 * rt + ln) * 40 + quad * 8];
#pragma unroll
        for (int ct = 0; ct < 2; ++ct)
            bf[ct] = *(const short8*)&Blds[(32 * wv + 16 * ct + ln) * 40 + quad * 8];
#pragma unroll
        for (int rt = 0; rt < 8; ++rt)
#pragma unroll
            for (int ct = 0; ct < 2; ++ct)
                acc[rt][ct] = __builtin_amdgcn_mfma_f32_16x16x32_bf16(af[rt], bf[ct], acc[rt][ct], 0, 0, 0);
        __syncthreads();
    }

    if (EPI == 1) {
        // rows 0..63 of tile are mag for bins kbase..kbase+63, rows 64..127 the phases
        const int kbase = m0 >> 1;   // 64*by
#pragma unroll
        for (int rt = 0; rt < 4; ++rt) {
#pragma unroll
            for (int reg = 0; reg < 4; ++reg) {
                const int rloc = 16 * rt + quad * 4 + reg;
                const int k = kbase + rloc;
                if (k >= KP2U) continue;
                const float bm = bp[m0 + rloc];
                const float bph = bp[m0 + 64 + rloc];
#pragma unroll
                for (int ct = 0; ct < 2; ++ct) {
                    const int l = l0 + 32 * wv + 16 * ct + ln;
                    const float hm = acc[rt][ct][reg] + bm;
                    const float hp = acc[rt + 4][ct][reg] + bph;
                    const float mag = fminf(__expf(hm), 100.0f);
                    const float re = mag * __cosf(hp);
                    const float im = mag * __sinf(hp);
                    Sout[((size_t)bz * LEN + l) * KP2U + k] =
                        (unsigned)f2bf(re) | ((unsigned)f2bf(im) << 16);
                }
            }
        }
    } else {
        float* yb = yout + (size_t)bz * OUTL;
#pragma unroll
        for (int rt = 0; rt < 8; ++rt)
#pragma unroll
            for (int ct = 0; ct < 2; ++ct) {
                const int l = l0 + 32 * wv + 16 * ct + ln;
#pragma unroll
                for (int reg = 0; reg < 4; ++reg) {
                    const int n = m0 + 16 * rt + quad * 4 + reg;
                    const unsigned jo = (unsigned)(256 * l + n - PADT);
                    if (jo < (unsigned)OUTL) atomicAdd(yb + jo, acc[rt][ct][reg]);
                }
            }
    }
}

// ---------------- finalize: divide by OLA envelope ---------------------------
__global__ void finalize_kernel(float* __restrict__ y) {
    const size_t idx = (size_t)blockIdx.x * 256 + threadIdx.x;   // 16*2^20 exact
    const int j = (int)(idx & (OUTL - 1));
    const int m = j + PADT;
    const int t1 = m >> 8;
    const int tlo = (t1 - 3 > 0) ? t1 - 3 : 0;
    const int thi = (t1 < 4095) ? t1 : 4095;
    float env;
    if (thi - tlo == 3) {
        env = 1.5f;                          // Hann^2 COLA at hop N/4
    } else {
        env = 0.f;
        for (int t = tlo; t <= thi; ++t) {
            const int n = m - 256 * t;
            const float w = 0.5f - 0.5f * __cosf((float)n * (6.283185307179586f / 1024.f));
            env += w * w;
        }
    }
    y[idx] /= env;
}

// ---------------- launch -----------------------------------------------------
// Workspace layout (needs ~209 MB):
//   xT  : 16*4096*512  bf16  =  67,108,864 B   @ 0
//   Wb  : 1152*512     bf16  =   1,179,648 B   @ 67,108,864
//   bp  : 1152         f32   =       4,608 B   @ 68,288,512
//   D   : 1024*1056    bf16  =   2,162,688 B   @ 68,293,120
//   S   : 16*4096*528  u32   = 138,412,032 B   @ 70,455,808
extern "C" void kernel_launch(void* const* d_in, const int* in_sizes, int n_in,
                              void* d_out, int out_size, void* d_ws, size_t ws_size,
                              hipStream_t stream) {
    const float* x    = (const float*)d_in[0];
    const float* W    = (const float*)d_in[1];
    const float* bvec = (const float*)d_in[2];
    float* y = (float*)d_out;
    char* ws = (char*)d_ws;

    unsigned short* xT = (unsigned short*)(ws);
    unsigned short* Wb = (unsigned short*)(ws + 67108864);
    float*          bp = (float*)(ws + 68288512);
    unsigned short* D  = (unsigned short*)(ws + 68293120);
    unsigned*       S  = (unsigned*)(ws + 70455808);

    hipMemsetAsync(d_out, 0, (size_t)out_size * sizeof(float), stream);

    transpose_x<<<dim3(128, 16, BATCH), dim3(32, 8), 0, stream>>>(x, xT);
    pack_W<<<dim3(1152), dim3(256), 0, stream>>>(W, bvec, Wb, bp);
    build_D<<<dim3((NFFT * KP2 + 255) / 256), dim3(256), 0, stream>>>(D);

    // GEMM1: h = Wb @ xT^T per batch, fused exp/clip/sincos -> S (bf16 complex)
    gemm_kernel<DIMK, 1><<<dim3(32, 9, BATCH), dim3(256), 0, stream>>>(
        Wb, xT, bp, S, nullptr);

    // GEMM2: frames = D @ S^T per batch, fused overlap-add into y
    gemm_kernel<KP2, 2><<<dim3(32, 8, BATCH), dim3(256), 0, stream>>>(
        D, (const unsigned short*)S, nullptr, nullptr, y);

    finalize_kernel<<<dim3((BATCH * OUTL) / 256), dim3(256), 0, stream>>>(y);
}

// Round 2
// 781.117 us; speedup vs baseline: 1.6214x; 1.6214x over previous
//
#include <hip/hip_runtime.h>
#include <cstdint>
#include <cstddef>

// ---------------- problem constants ----------------
#define BATCH  16
#define DIMK   512
#define LEN    4096        // frames T == L
#define NFFT   1024
#define HOPS   256
#define PADT   384         // (WIN-HOP)/2
#define OUTL   1048576     // per-batch output length = L*HOP
#define KP2    1056        // S row: 528 complex bins interleaved (513 used + pad)
#define KP2U   528         // uint32 words per S row
#define K2     4224        // GEMM2 K = 4*1056 (r-segments)

typedef __attribute__((ext_vector_type(8))) short  short8;
typedef __attribute__((ext_vector_type(4))) float  f32x4;

__device__ __forceinline__ unsigned short f2bf(float f) {
    unsigned u = __float_as_uint(f);
    u += 0x7FFFu + ((u >> 16) & 1u);     // RNE
    return (unsigned short)(u >> 16);
}

// ---------------- pack W (gather mag/phase rows pairwise into M-tiles) -------
// Wb row r (r = 128*i + j): j<64 -> W[64i+j] (mag bin 64i+j), j>=64 -> W[1024+64i+j-64]
__global__ void pack_W(const float* __restrict__ W, const float* __restrict__ bvec,
                       unsigned short* __restrict__ Wb, float* __restrict__ bp) {
    const int r = blockIdx.x;               // 0..1151
    const int i = r >> 7, j = r & 127;
    const int src = (j < 64) ? (i * 64 + j) : (1024 + i * 64 + (j - 64));
    for (int c = threadIdx.x; c < DIMK; c += 256)
        Wb[r * DIMK + c] = f2bf(W[src * DIMK + c]);
    if (threadIdx.x == 0) bp[r] = bvec[src];
}

// ---------------- transpose x (B,512,L) f32 -> xT (B,L,512) bf16 -------------
__global__ void transpose_x(const float* __restrict__ x, unsigned short* __restrict__ xT) {
    __shared__ float tile[32][33];
    const int b = blockIdx.z;
    const int l0 = blockIdx.x * 32, d0 = blockIdx.y * 32;
    const int tx = threadIdx.x, ty = threadIdx.y;        // 32 x 8
#pragma unroll
    for (int i = 0; i < 4; ++i)
        tile[ty + 8 * i][tx] = x[((size_t)b * DIMK + d0 + ty + 8 * i) * LEN + l0 + tx];
    __syncthreads();
#pragma unroll
    for (int i = 0; i < 4; ++i)
        xT[((size_t)b * LEN + l0 + ty + 8 * i) * DIMK + d0 + tx] = f2bf(tile[tx][ty + 8 * i]);
}

// ---------------- build D' : 256 x 4224 bf16 ---------------------------------
// D'[s, r*1056 + jj] = windowed-irfft coeff for frame sample n = s + 256*r, bin jj
// frames[n] = w[n]/1024 * [ Re0 + (-1)^n Re512 + sum_{k=1}^{511} 2(Rek cos - Imk sin) ]
__global__ void build_D(unsigned short* __restrict__ D) {
    const int idx = blockIdx.x * 256 + threadIdx.x;
    if (idx >= 256 * K2) return;
    const int srow = idx / K2;
    const int col  = idx - srow * K2;
    const int rseg = col / KP2;
    const int jj   = col - rseg * KP2;
    const int n    = srow + 256 * rseg;
    const int k    = jj >> 1;
    const float wv = 0.5f - 0.5f * __cosf((float)n * (6.283185307179586f / 1024.f));
    float v = 0.f;
    if ((jj & 1) == 0) {                                  // Re coefficient
        if (k == 0)        v = wv * (1.f / 1024.f);
        else if (k < 512) {
            const int p = (k * n) & 1023;
            v = 2.f * __cosf((float)p * (6.283185307179586f / 1024.f)) * wv * (1.f / 1024.f);
        } else if (k == 512) v = ((n & 1) ? -wv : wv) * (1.f / 1024.f);
    } else {                                              // Im coefficient
        if (k >= 1 && k < 512) {
            const int p = (k * n) & 1023;
            v = -2.f * __sinf((float)p * (6.283185307179586f / 1024.f)) * wv * (1.f / 1024.f);
        }
    }
    D[idx] = f2bf(v);
}

// ---------------- GEMM1: h = Wb @ xT^T, fused exp/clip/sincos -> S -----------
__global__ __launch_bounds__(256)
void gemm1_kernel(const unsigned short* __restrict__ A,
                  const unsigned short* __restrict__ Bm,
                  const float* __restrict__ bp,
                  unsigned* __restrict__ Sout)
{
    __shared__ alignas(16) unsigned short Alds[128 * 40];   // +8 pad: 2-way banks only
    __shared__ alignas(16) unsigned short Blds[128 * 40];

    const int tid  = threadIdx.x;
    const int lane = tid & 63, wv = tid >> 6;
    const int quad = lane >> 4, ln = lane & 15;
    const int bx = blockIdx.x, by = blockIdx.y, bz = blockIdx.z;
    const int m0 = by * 128, l0 = bx * 128;

    // 512 16B-chunks per tile: chunk c -> row c>>2, kchunk (c&3)*8
    const int r0 = tid >> 2,        kc0 = (tid & 3) * 8;
    const int r1 = (tid + 256) >> 2, kc1 = kc0;   // second chunk: rows 64..127

    const size_t bbase = (size_t)bz * LEN * DIMK;

    f32x4 acc[8][2];
#pragma unroll
    for (int a = 0; a < 8; ++a)
#pragma unroll
        for (int c = 0; c < 2; ++c) acc[a][c] = (f32x4){0.f, 0.f, 0.f, 0.f};

    for (int k0 = 0; k0 < DIMK; k0 += 32) {
        *(uint4*)&Alds[r0 * 40 + kc0] = *(const uint4*)&A[(size_t)(m0 + r0) * DIMK + k0 + kc0];
        *(uint4*)&Alds[r1 * 40 + kc1] = *(const uint4*)&A[(size_t)(m0 + r1) * DIMK + k0 + kc1];
        *(uint4*)&Blds[r0 * 40 + kc0] = *(const uint4*)&Bm[bbase + (size_t)(l0 + r0) * DIMK + k0 + kc0];
        *(uint4*)&Blds[r1 * 40 + kc1] = *(const uint4*)&Bm[bbase + (size_t)(l0 + r1) * DIMK + k0 + kc1];
        __syncthreads();

        short8 af[8], bfr[2];
#pragma unroll
        for (int rt = 0; rt < 8; ++rt)
            af[rt] = *(const short8*)&Alds[(16 * rt + ln) * 40 + quad * 8];
#pragma unroll
        for (int ct = 0; ct < 2; ++ct)
            bfr[ct] = *(const short8*)&Blds[(32 * wv + 16 * ct + ln) * 40 + quad * 8];
#pragma unroll
        for (int rt = 0; rt < 8; ++rt)
#pragma unroll
            for (int ct = 0; ct < 2; ++ct)
                acc[rt][ct] = __builtin_amdgcn_mfma_f32_16x16x32_bf16(af[rt], bfr[ct], acc[rt][ct], 0, 0, 0);
        __syncthreads();
    }

    // rows 0..63 of tile are mag for bins kbase..kbase+63, rows 64..127 the phases
    const int kbase = m0 >> 1;   // 64*by
#pragma unroll
    for (int rt = 0; rt < 4; ++rt) {
#pragma unroll
        for (int reg = 0; reg < 4; ++reg) {
            const int rloc = 16 * rt + quad * 4 + reg;
            const int k = kbase + rloc;
            if (k >= KP2U) continue;
            const float bm  = bp[m0 + rloc];
            const float bph = bp[m0 + 64 + rloc];
#pragma unroll
            for (int ct = 0; ct < 2; ++ct) {
                const int l = l0 + 32 * wv + 16 * ct + ln;
                const float hm = acc[rt][ct][reg] + bm;
                const float hp = acc[rt + 4][ct][reg] + bph;
                const float mag = fminf(__expf(hm), 100.0f);
                const float re = mag * __cosf(hp);
                const float im = mag * __sinf(hp);
                Sout[((size_t)bz * LEN + l) * KP2U + k] =
                    (unsigned)f2bf(re) | ((unsigned)f2bf(im) << 16);
            }
        }
    }
}

// ---------------- OLA envelope (edges only; interior = 1.5 by COLA) ----------
__device__ __forceinline__ float env_at(int q, int s) {
    if (q >= 3 && q <= 4095) return 1.5f;
    float env = 0.f;
#pragma unroll
    for (int r = 0; r < 4; ++r) {
        const int t = q - r;
        if (t >= 0 && t < LEN) {
            const float w = 0.5f - 0.5f * __cosf((float)(s + 256 * r) * (6.283185307179586f / 1024.f));
            env += w * w;
        }
    }
    return env;
}

// ---------------- GEMM2: y[256q+s-384] = sum_r sum_k D'[s,r,k] S[k, q-r] -----
// A: D' 256 x 4224.  B: S rows (bz*LEN + l_eff)*1056 bf16 with l_eff = q - rseg.
// Each output element written exactly once (coalesced by L2), env fused.
__global__ __launch_bounds__(256)
void gemm2_kernel(const unsigned short* __restrict__ A,
                  const unsigned short* __restrict__ Sm,
                  float* __restrict__ yout)
{
    __shared__ alignas(16) unsigned short Alds[128 * 40];
    __shared__ alignas(16) unsigned short Blds[128 * 40];

    const int tid  = threadIdx.x;
    const int lane = tid & 63, wv = tid >> 6;
    const int quad = lane >> 4, ln = lane & 15;
    const int bx = blockIdx.x, by = blockIdx.y, bz = blockIdx.z;
    const int m0 = by * 128;          // s-tile base (0 or 128)
    const int qt0 = bx * 128;         // qi-tile base, qi = q - 1

    const int r0 = tid >> 2,         kc0 = (tid & 3) * 8;
    const int r1 = (tid + 256) >> 2, kc1 = kc0;

    const size_t sbase = (size_t)bz * LEN * KP2;

    f32x4 acc[8][2];
#pragma unroll
    for (int a = 0; a < 8; ++a)
#pragma unroll
        for (int c = 0; c < 2; ++c) acc[a][c] = (f32x4){0.f, 0.f, 0.f, 0.f};

    for (int k0 = 0; k0 < K2; k0 += 32) {
        const int rseg = k0 / KP2;            // 0..3 (1056 = 33*32, so uniform per chunk)
        const int kk   = k0 - rseg * KP2;

        *(uint4*)&Alds[r0 * 40 + kc0] = *(const uint4*)&A[(size_t)(m0 + r0) * K2 + k0 + kc0];
        *(uint4*)&Alds[r1 * 40 + kc1] = *(const uint4*)&A[(size_t)(m0 + r1) * K2 + k0 + kc1];

        const int le0 = qt0 + 1 - rseg + r0;  // l_eff for this row
        const int le1 = qt0 + 1 - rseg + r1;
        if ((unsigned)le0 < (unsigned)LEN)
            *(uint4*)&Blds[r0 * 40 + kc0] = *(const uint4*)&Sm[sbase + (size_t)le0 * KP2 + kk + kc0];
        else
            *(uint4*)&Blds[r0 * 40 + kc0] = (uint4){0, 0, 0, 0};
        if ((unsigned)le1 < (unsigned)LEN)
            *(uint4*)&Blds[r1 * 40 + kc1] = *(const uint4*)&Sm[sbase + (size_t)le1 * KP2 + kk + kc1];
        else
            *(uint4*)&Blds[r1 * 40 + kc1] = (uint4){0, 0, 0, 0};
        __syncthreads();

        short8 af[8], bfr[2];
#pragma unroll
        for (int rt = 0; rt < 8; ++rt)
            af[rt] = *(const short8*)&Alds[(16 * rt + ln) * 40 + quad * 8];
#pragma unroll
        for (int ct = 0; ct < 2; ++ct)
            bfr[ct] = *(const short8*)&Blds[(32 * wv + 16 * ct + ln) * 40 + quad * 8];
#pragma unroll
        for (int rt = 0; rt < 8; ++rt)
#pragma unroll
            for (int ct = 0; ct < 2; ++ct)
                acc[rt][ct] = __builtin_amdgcn_mfma_f32_16x16x32_bf16(af[rt], bfr[ct], acc[rt][ct], 0, 0, 0);
        __syncthreads();
    }

    float* yb = yout + (size_t)bz * OUTL;
#pragma unroll
    for (int rt = 0; rt < 8; ++rt)
#pragma unroll
        for (int ct = 0; ct < 2; ++ct) {
            const int qi = qt0 + 32 * wv + 16 * ct + ln;
            const int q  = qi + 1;
#pragma unroll
            for (int reg = 0; reg < 4; ++reg) {
                const int s = m0 + 16 * rt + quad * 4 + reg;
                const int j = 256 * qi + s - 128;          // = 256*q + s - 384
                if ((unsigned)j < (unsigned)OUTL)
                    yb[j] = acc[rt][ct][reg] / env_at(q, s);
            }
        }
}

// ---------------- launch -----------------------------------------------------
// Workspace layout (~209 MB):
//   xT  : 16*4096*512  bf16  =  67,108,864 B   @ 0
//   Wb  : 1152*512     bf16  =   1,179,648 B   @ 67,108,864
//   bp  : 1152         f32   =       4,608 B   @ 68,288,512
//   D'  : 256*4224     bf16  =   2,162,688 B   @ 68,293,120
//   S   : 16*4096*528  u32   = 138,412,032 B   @ 70,455,808
extern "C" void kernel_launch(void* const* d_in, const int* in_sizes, int n_in,
                              void* d_out, int out_size, void* d_ws, size_t ws_size,
                              hipStream_t stream) {
    const float* x    = (const float*)d_in[0];
    const float* W    = (const float*)d_in[1];
    const float* bvec = (const float*)d_in[2];
    float* y = (float*)d_out;
    char* ws = (char*)d_ws;

    unsigned short* xT = (unsigned short*)(ws);
    unsigned short* Wb = (unsigned short*)(ws + 67108864);
    float*          bp = (float*)(ws + 68288512);
    unsigned short* D  = (unsigned short*)(ws + 68293120);
    unsigned*       S  = (unsigned*)(ws + 70455808);

    transpose_x<<<dim3(128, 16, BATCH), dim3(32, 8), 0, stream>>>(x, xT);
    pack_W<<<dim3(1152), dim3(256), 0, stream>>>(W, bvec, Wb, bp);
    build_D<<<dim3((256 * K2 + 255) / 256), dim3(256), 0, stream>>>(D);

    // GEMM1: h = Wb @ xT^T per batch, fused exp/clip/sincos -> S (bf16 complex)
    gemm1_kernel<<<dim3(32, 9, BATCH), dim3(256), 0, stream>>>(Wb, xT, bp, S);

    // GEMM2: gather-OLA GEMM, env fused, every output written exactly once
    gemm2_kernel<<<dim3(33, 2, BATCH), dim3(256), 0, stream>>>(
        D, (const unsigned short*)S, y);
}

// Round 3
// 592.581 us; speedup vs baseline: 2.1373x; 1.3182x over previous
//
#include <hip/hip_runtime.h>
#include <cstdint>
#include <cstddef>

// ---------------- problem constants ----------------
#define BATCH  16
#define DIMK   512
#define LEN    4096        // frames T == L
#define NFFT   1024
#define HOPS   256
#define PADT   384         // (WIN-HOP)/2
#define OUTL   1048576     // per-batch output length = L*HOP
#define KP2    1056        // S row: 528 complex bins interleaved (513 used + pad)
#define KP2U   528         // uint32 words per S row
#define K2     4224        // D' row length = 4*1056 (r-segments)

typedef __attribute__((ext_vector_type(8))) short  short8;
typedef __attribute__((ext_vector_type(4))) float  f32x4;

__device__ __forceinline__ unsigned short f2bf(float f) {
    unsigned u = __float_as_uint(f);
    u += 0x7FFFu + ((u >> 16) & 1u);     // RNE
    return (unsigned short)(u >> 16);
}

// async global->LDS, 16B per lane; LDS dest is wave-uniform base + lane*16,
// which matches chunk-linear LDS layouts (chunk c at byte offset c*16).
__device__ __forceinline__ void gld16(const unsigned short* g, unsigned short* l) {
    __builtin_amdgcn_global_load_lds(
        (const __attribute__((address_space(1))) unsigned int*)(const void*)g,
        (__attribute__((address_space(3))) unsigned int*)(void*)l, 16, 0, 0);
}

// ---------------- pack W (gather mag/phase rows pairwise into M-tiles) -------
// Wb row r (r = 128*i + j): j<64 -> W[64i+j] (mag bin 64i+j), j>=64 -> W[1024+64i+j-64]
__global__ void pack_W(const float* __restrict__ W, const float* __restrict__ bvec,
                       unsigned short* __restrict__ Wb, float* __restrict__ bp) {
    const int r = blockIdx.x;               // 0..1151
    const int i = r >> 7, j = r & 127;
    const int src = (j < 64) ? (i * 64 + j) : (1024 + i * 64 + (j - 64));
    for (int c = threadIdx.x; c < DIMK; c += 256)
        Wb[r * DIMK + c] = f2bf(W[src * DIMK + c]);
    if (threadIdx.x == 0) bp[r] = bvec[src];
}

// ---------------- transpose x (B,512,L) f32 -> xT (B,L,512) bf16 -------------
__global__ void transpose_x(const float* __restrict__ x, unsigned short* __restrict__ xT) {
    __shared__ float tile[32][33];
    const int b = blockIdx.z;
    const int l0 = blockIdx.x * 32, d0 = blockIdx.y * 32;
    const int tx = threadIdx.x, ty = threadIdx.y;        // 32 x 8
#pragma unroll
    for (int i = 0; i < 4; ++i)
        tile[ty + 8 * i][tx] = x[((size_t)b * DIMK + d0 + ty + 8 * i) * LEN + l0 + tx];
    __syncthreads();
#pragma unroll
    for (int i = 0; i < 4; ++i)
        xT[((size_t)b * LEN + l0 + ty + 8 * i) * DIMK + d0 + tx] = f2bf(tile[tx][ty + 8 * i]);
}

// ---------------- build D' : 256 x 4224 bf16 ---------------------------------
// D'[s, r*1056 + jj] = windowed-irfft coeff for frame sample n = s + 256*r, bin jj
__global__ void build_D(unsigned short* __restrict__ D) {
    const int idx = blockIdx.x * 256 + threadIdx.x;
    if (idx >= 256 * K2) return;
    const int srow = idx / K2;
    const int col  = idx - srow * K2;
    const int rseg = col / KP2;
    const int jj   = col - rseg * KP2;
    const int n    = srow + 256 * rseg;
    const int k    = jj >> 1;
    const float wv = 0.5f - 0.5f * __cosf((float)n * (6.283185307179586f / 1024.f));
    float v = 0.f;
    if ((jj & 1) == 0) {                                  // Re coefficient
        if (k == 0)        v = wv * (1.f / 1024.f);
        else if (k < 512) {
            const int p = (k * n) & 1023;
            v = 2.f * __cosf((float)p * (6.283185307179586f / 1024.f)) * wv * (1.f / 1024.f);
        } else if (k == 512) v = ((n & 1) ? -wv : wv) * (1.f / 1024.f);
    } else {                                              // Im coefficient
        if (k >= 1 && k < 512) {
            const int p = (k * n) & 1023;
            v = -2.f * __sinf((float)p * (6.283185307179586f / 1024.f)) * wv * (1.f / 1024.f);
        }
    }
    D[idx] = f2bf(v);
}

// ---------------- GEMM1: h = Wb @ xT^T, fused exp/clip/sincos -> S -----------
__global__ __launch_bounds__(256)
void gemm1_kernel(const unsigned short* __restrict__ A,
                  const unsigned short* __restrict__ Bm,
                  const float* __restrict__ bp,
                  unsigned* __restrict__ Sout)
{
    __shared__ alignas(16) unsigned short Alds[128 * 32];
    __shared__ alignas(16) unsigned short Blds[128 * 32];

    const int tid  = threadIdx.x;
    const int lane = tid & 63, w = tid >> 6;
    const int quad = lane >> 4, ln = lane & 15;
    const int bx = blockIdx.x, by = blockIdx.y, bz = blockIdx.z;
    const int m0 = by * 128, l0 = bx * 128;

    // chunk c (16B) -> row c>>2, col chunk c&3; LDS byte offset c*16
    const int c0 = tid, c1 = tid + 256;
    const unsigned short* Asrc0 = A + (size_t)(m0 + (c0 >> 2)) * DIMK + (c0 & 3) * 8;
    const unsigned short* Asrc1 = A + (size_t)(m0 + (c1 >> 2)) * DIMK + (c1 & 3) * 8;
    const unsigned short* Bsrc0 = Bm + ((size_t)bz * LEN + l0 + (c0 >> 2)) * DIMK + (c0 & 3) * 8;
    const unsigned short* Bsrc1 = Bm + ((size_t)bz * LEN + l0 + (c1 >> 2)) * DIMK + (c1 & 3) * 8;

    f32x4 acc[8][2];
#pragma unroll
    for (int a = 0; a < 8; ++a)
#pragma unroll
        for (int c = 0; c < 2; ++c) acc[a][c] = (f32x4){0.f, 0.f, 0.f, 0.f};

    for (int k0 = 0; k0 < DIMK; k0 += 32) {
        gld16(Asrc0 + k0, &Alds[c0 * 8]);
        gld16(Asrc1 + k0, &Alds[c1 * 8]);
        gld16(Bsrc0 + k0, &Blds[c0 * 8]);
        gld16(Bsrc1 + k0, &Blds[c1 * 8]);
        __syncthreads();

        short8 af[8], bfr[2];
#pragma unroll
        for (int rt = 0; rt < 8; ++rt)
            af[rt] = *(const short8*)&Alds[(16 * rt + ln) * 32 + quad * 8];
#pragma unroll
        for (int ct = 0; ct < 2; ++ct)
            bfr[ct] = *(const short8*)&Blds[(32 * w + 16 * ct + ln) * 32 + quad * 8];
#pragma unroll
        for (int rt = 0; rt < 8; ++rt)
#pragma unroll
            for (int ct = 0; ct < 2; ++ct)
                acc[rt][ct] = __builtin_amdgcn_mfma_f32_16x16x32_bf16(af[rt], bfr[ct], acc[rt][ct], 0, 0, 0);
        __syncthreads();
    }

    const int kbase = m0 >> 1;   // 64*by
#pragma unroll
    for (int rt = 0; rt < 4; ++rt) {
#pragma unroll
        for (int reg = 0; reg < 4; ++reg) {
            const int rloc = 16 * rt + quad * 4 + reg;
            const int k = kbase + rloc;
            if (k >= KP2U) continue;
            const float bm  = bp[m0 + rloc];
            const float bph = bp[m0 + 64 + rloc];
#pragma unroll
            for (int ct = 0; ct < 2; ++ct) {
                const int l = l0 + 32 * w + 16 * ct + ln;
                const float hm = acc[rt][ct][reg] + bm;
                const float hp = acc[rt + 4][ct][reg] + bph;
                const float mag = fminf(__expf(hm), 100.0f);
                const float re = mag * __cosf(hp);
                const float im = mag * __sinf(hp);
                Sout[((size_t)bz * LEN + l) * KP2U + k] =
                    (unsigned)f2bf(re) | ((unsigned)f2bf(im) << 16);
            }
        }
    }
}

// ---------------- OLA envelope (edges only; interior = 1.5 by COLA) ----------
__device__ __forceinline__ float env_at(int q, int s) {
    if (q >= 3 && q <= 4095) return 1.5f;
    float env = 0.f;
#pragma unroll
    for (int r = 0; r < 4; ++r) {
        const int t = q - r;
        if (t >= 0 && t < LEN) {
            const float w = 0.5f - 0.5f * __cosf((float)(s + 256 * r) * (6.283185307179586f / 1024.f));
            env += w * w;
        }
    }
    return env;
}

// ---------------- GEMM2: y[256q+s-384] = sum_r sum_k D'[s,r,k] S[k, q-r] -----
// One B-tile (132 S rows x 32 cols) staged per kk, reused by all 4 r-segments
// with an LDS row shift of (3 - rseg).  A (D') staged per rseg via gld16.
// Output tile: 128 s (by) x 128 qi (bx); waves 2x2 (s-half x qi-half).
__global__ __launch_bounds__(256)
void gemm2_kernel(const unsigned short* __restrict__ D,   // 256 x 4224
                  const unsigned short* __restrict__ Sm,  // (bz*LEN + l)*1056 bf16
                  float* __restrict__ yout)
{
    __shared__ alignas(16) unsigned short Alds[4 * 128 * 32];  // [rseg][row][32]
    __shared__ alignas(16) unsigned short Blds[132 * 32];      // [rho][32]

    const int tid  = threadIdx.x;
    const int lane = tid & 63, w = tid >> 6;
    const int quad = lane >> 4, ln = lane & 15;
    const int sh = w >> 1, qh = w & 1;
    const int bx = blockIdx.x, by = blockIdx.y, bz = blockIdx.z;
    const int qt0 = bx * 128, s0 = by * 128;

    const size_t srowbase = (size_t)bz * LEN;

    f32x4 acc[4][4];
#pragma unroll
    for (int a = 0; a < 4; ++a)
#pragma unroll
        for (int c = 0; c < 4; ++c) acc[a][c] = (f32x4){0.f, 0.f, 0.f, 0.f};

    for (int kk = 0; kk < KP2; kk += 32) {
        // ---- stage A: 2048 chunks, 8 per thread, chunk-linear LDS ----
#pragma unroll
        for (int i = 0; i < 8; ++i) {
            const int ca = i * 256 + tid;
            const int rseg = ca >> 9, rem = ca & 511;
            const int row = rem >> 2, cq = rem & 3;
            gld16(D + (size_t)(s0 + row) * K2 + rseg * KP2 + kk + cq * 8,
                  &Alds[ca * 8]);
        }
        // ---- stage B: 528 chunks (132 rows), manual with OOB predication ----
        {
            const int cb0 = tid, cb1 = tid + 256;
            const int r0 = cb0 >> 2, q0 = cb0 & 3, le0 = qt0 + r0 - 2;
            const int r1 = cb1 >> 2, q1 = cb1 & 3, le1 = qt0 + r1 - 2;
            uint4 v0 = {0, 0, 0, 0}, v1 = {0, 0, 0, 0};
            if ((unsigned)le0 < (unsigned)LEN)
                v0 = *(const uint4*)&Sm[(srowbase + le0) * KP2 + kk + q0 * 8];
            if ((unsigned)le1 < (unsigned)LEN)
                v1 = *(const uint4*)&Sm[(srowbase + le1) * KP2 + kk + q1 * 8];
            *(uint4*)&Blds[cb0 * 8] = v0;
            *(uint4*)&Blds[cb1 * 8] = v1;
            if (tid < 16) {
                const int cb2 = 512 + tid;
                const int r2 = cb2 >> 2, q2 = cb2 & 3, le2 = qt0 + r2 - 2;
                uint4 v2 = {0, 0, 0, 0};
                if ((unsigned)le2 < (unsigned)LEN)
                    v2 = *(const uint4*)&Sm[(srowbase + le2) * KP2 + kk + q2 * 8];
                *(uint4*)&Blds[cb2 * 8] = v2;
            }
        }
        __syncthreads();

#pragma unroll
        for (int rseg = 0; rseg < 4; ++rseg) {
            short8 af[4], bfr[4];
#pragma unroll
            for (int rt = 0; rt < 4; ++rt)
                af[rt] = *(const short8*)&Alds[rseg * 4096 + (64 * sh + 16 * rt + ln) * 32 + quad * 8];
#pragma unroll
            for (int ct = 0; ct < 4; ++ct)
                bfr[ct] = *(const short8*)&Blds[(3 - rseg + 64 * qh + 16 * ct + ln) * 32 + quad * 8];
#pragma unroll
            for (int rt = 0; rt < 4; ++rt)
#pragma unroll
                for (int ct = 0; ct < 4; ++ct)
                    acc[rt][ct] = __builtin_amdgcn_mfma_f32_16x16x32_bf16(af[rt], bfr[ct], acc[rt][ct], 0, 0, 0);
        }
        __syncthreads();
    }

    float* yb = yout + (size_t)bz * OUTL;
#pragma unroll
    for (int rt = 0; rt < 4; ++rt)
#pragma unroll
        for (int ct = 0; ct < 4; ++ct) {
            const int qi = qt0 + 64 * qh + 16 * ct + ln;
            const int q  = qi + 1;
#pragma unroll
            for (int reg = 0; reg < 4; ++reg) {
                const int s = s0 + 64 * sh + 16 * rt + quad * 4 + reg;
                const int j = 256 * qi + s - 128;          // = 256*q + s - 384
                if ((unsigned)j < (unsigned)OUTL)
                    yb[j] = acc[rt][ct][reg] / env_at(q, s);
            }
        }
}

// ---------------- launch -----------------------------------------------------
// Workspace layout (~209 MB):
//   xT  : 16*4096*512  bf16  =  67,108,864 B   @ 0
//   Wb  : 1152*512     bf16  =   1,179,648 B   @ 67,108,864
//   bp  : 1152         f32   =       4,608 B   @ 68,288,512
//   D'  : 256*4224     bf16  =   2,162,688 B   @ 68,293,120
//   S   : 16*4096*528  u32   = 138,412,032 B   @ 70,455,808
extern "C" void kernel_launch(void* const* d_in, const int* in_sizes, int n_in,
                              void* d_out, int out_size, void* d_ws, size_t ws_size,
                              hipStream_t stream) {
    const float* x    = (const float*)d_in[0];
    const float* W    = (const float*)d_in[1];
    const float* bvec = (const float*)d_in[2];
    float* y = (float*)d_out;
    char* ws = (char*)d_ws;

    unsigned short* xT = (unsigned short*)(ws);
    unsigned short* Wb = (unsigned short*)(ws + 67108864);
    float*          bp = (float*)(ws + 68288512);
    unsigned short* D  = (unsigned short*)(ws + 68293120);
    unsigned*       S  = (unsigned*)(ws + 70455808);

    transpose_x<<<dim3(128, 16, BATCH), dim3(32, 8), 0, stream>>>(x, xT);
    pack_W<<<dim3(1152), dim3(256), 0, stream>>>(W, bvec, Wb, bp);
    build_D<<<dim3((256 * K2 + 255) / 256), dim3(256), 0, stream>>>(D);

    // GEMM1: h = Wb @ xT^T per batch, fused exp/clip/sincos -> S (bf16 complex)
    gemm1_kernel<<<dim3(32, 9, BATCH), dim3(256), 0, stream>>>(Wb, xT, bp, S);

    // GEMM2: gather-OLA GEMM, B-tile shared across 4 r-segments, env fused
    gemm2_kernel<<<dim3(33, 2, BATCH), dim3(256), 0, stream>>>(
        D, (const unsigned short*)S, y);
}

// Round 4
// 529.531 us; speedup vs baseline: 2.3918x; 1.1191x over previous
//
#include <hip/hip_runtime.h>
#include <cstdint>
#include <cstddef>

// ---------------- problem constants ----------------
#define BATCH  16
#define DIMK   512
#define LEN    4096        // frames T == L
#define NFFT   1024
#define HOPS   256
#define PADT   384         // (WIN-HOP)/2
#define OUTL   1048576     // per-batch output length = L*HOP
#define KP2    1056        // S row: 528 complex bins interleaved (513 used + pad)
#define KP2U   528         // uint32 words per S row
#define K2     4224        // D' row length = 4*1056 (r-segments)

typedef __attribute__((ext_vector_type(8))) short  short8;
typedef __attribute__((ext_vector_type(4))) float  f32x4;

__device__ __forceinline__ unsigned short f2bf(float f) {
    unsigned u = __float_as_uint(f);
    u += 0x7FFFu + ((u >> 16) & 1u);     // RNE
    return (unsigned short)(u >> 16);
}

// async global->LDS, 16B per lane; LDS dest is wave-uniform base + lane*16.
__device__ __forceinline__ void gld16(const unsigned short* g, unsigned short* l) {
    __builtin_amdgcn_global_load_lds(
        (const __attribute__((address_space(1))) unsigned int*)(const void*)g,
        (__attribute__((address_space(3))) unsigned int*)(void*)l, 16, 0, 0);
}

// ---------------- pack W (gather mag/phase rows pairwise into M-tiles) -------
__global__ void pack_W(const float* __restrict__ W, const float* __restrict__ bvec,
                       unsigned short* __restrict__ Wb, float* __restrict__ bp) {
    const int r = blockIdx.x;               // 0..1151
    const int i = r >> 7, j = r & 127;
    const int src = (j < 64) ? (i * 64 + j) : (1024 + i * 64 + (j - 64));
    for (int c = threadIdx.x; c < DIMK; c += 256)
        Wb[r * DIMK + c] = f2bf(W[src * DIMK + c]);
    if (threadIdx.x == 0) bp[r] = bvec[src];
}

// ---------------- transpose x (B,512,L) f32 -> xT (B,L,512) bf16 -------------
__global__ void transpose_x(const float* __restrict__ x, unsigned short* __restrict__ xT) {
    __shared__ float tile[32][33];
    const int b = blockIdx.z;
    const int l0 = blockIdx.x * 32, d0 = blockIdx.y * 32;
    const int tx = threadIdx.x, ty = threadIdx.y;        // 32 x 8
#pragma unroll
    for (int i = 0; i < 4; ++i)
        tile[ty + 8 * i][tx] = x[((size_t)b * DIMK + d0 + ty + 8 * i) * LEN + l0 + tx];
    __syncthreads();
#pragma unroll
    for (int i = 0; i < 4; ++i)
        xT[((size_t)b * LEN + l0 + ty + 8 * i) * DIMK + d0 + tx] = f2bf(tile[tx][ty + 8 * i]);
}

// ---------------- build D' : 256 x 4224 bf16 ---------------------------------
__global__ void build_D(unsigned short* __restrict__ D) {
    const int idx = blockIdx.x * 256 + threadIdx.x;
    if (idx >= 256 * K2) return;
    const int srow = idx / K2;
    const int col  = idx - srow * K2;
    const int rseg = col / KP2;
    const int jj   = col - rseg * KP2;
    const int n    = srow + 256 * rseg;
    const int k    = jj >> 1;
    const float wv = 0.5f - 0.5f * __cosf((float)n * (6.283185307179586f / 1024.f));
    float v = 0.f;
    if ((jj & 1) == 0) {                                  // Re coefficient
        if (k == 0)        v = wv * (1.f / 1024.f);
        else if (k < 512) {
            const int p = (k * n) & 1023;
            v = 2.f * __cosf((float)p * (6.283185307179586f / 1024.f)) * wv * (1.f / 1024.f);
        } else if (k == 512) v = ((n & 1) ? -wv : wv) * (1.f / 1024.f);
    } else {                                              // Im coefficient
        if (k >= 1 && k < 512) {
            const int p = (k * n) & 1023;
            v = -2.f * __sinf((float)p * (6.283185307179586f / 1024.f)) * wv * (1.f / 1024.f);
        }
    }
    D[idx] = f2bf(v);
}

// ---------------- GEMM1: h = Wb @ xT^T, fused exp/clip/sincos -> S -----------
// Block covers 3 m-tiles (by*3 .. by*3+2) sequentially: B-tile re-staged per
// m-pass but passes 2-3 hit the block's own XCD L2 (guaranteed locality).
// Epilogue: LDS transpose (stride 68 dwords) -> coalesced 256B S stores.
__global__ __launch_bounds__(256)
void gemm1_kernel(const unsigned short* __restrict__ A,
                  const unsigned short* __restrict__ Bm,
                  const float* __restrict__ bp,
                  unsigned* __restrict__ Sout)
{
    __shared__ alignas(16) char smem[17408];
    unsigned short* Alds = (unsigned short*)smem;            // 8192 B
    unsigned short* Blds = (unsigned short*)(smem + 8192);   // 8192 B
    unsigned*       epi  = (unsigned*)smem;                  // 64 x 68 u32 = 17408 B

    const int tid  = threadIdx.x;
    const int lane = tid & 63, w = tid >> 6;
    const int quad = lane >> 4, ln = lane & 15;
    const int bx = blockIdx.x, by = blockIdx.y, bz = blockIdx.z;
    const int l0 = bx * 128;

    const int c0 = tid, c1 = tid + 256;    // chunk -> row c>>2, colchunk c&3
    const unsigned short* Bsrc0 = Bm + ((size_t)bz * LEN + l0 + (c0 >> 2)) * DIMK + (c0 & 3) * 8;
    const unsigned short* Bsrc1 = Bm + ((size_t)bz * LEN + l0 + (c1 >> 2)) * DIMK + (c1 & 3) * 8;

    for (int mi = 0; mi < 3; ++mi) {
        const int mt = by * 3 + mi;
        const int m0 = mt * 128;
        const int kbase = mt * 64;

        const unsigned short* Asrc0 = A + (size_t)(m0 + (c0 >> 2)) * DIMK + (c0 & 3) * 8;
        const unsigned short* Asrc1 = A + (size_t)(m0 + (c1 >> 2)) * DIMK + (c1 & 3) * 8;

        f32x4 acc[8][2];
#pragma unroll
        for (int a = 0; a < 8; ++a)
#pragma unroll
            for (int c = 0; c < 2; ++c) acc[a][c] = (f32x4){0.f, 0.f, 0.f, 0.f};

        for (int k0 = 0; k0 < DIMK; k0 += 32) {
            gld16(Asrc0 + k0, &Alds[c0 * 8]);
            gld16(Asrc1 + k0, &Alds[c1 * 8]);
            gld16(Bsrc0 + k0, &Blds[c0 * 8]);
            gld16(Bsrc1 + k0, &Blds[c1 * 8]);
            __syncthreads();

            short8 af[8], bfr[2];
#pragma unroll
            for (int rt = 0; rt < 8; ++rt)
                af[rt] = *(const short8*)&Alds[((16 * rt + ln) * 4 + quad) * 8];
#pragma unroll
            for (int ct = 0; ct < 2; ++ct)
                bfr[ct] = *(const short8*)&Blds[((32 * w + 16 * ct + ln) * 4 + quad) * 8];
#pragma unroll
            for (int rt = 0; rt < 8; ++rt)
#pragma unroll
                for (int ct = 0; ct < 2; ++ct)
                    acc[rt][ct] = __builtin_amdgcn_mfma_f32_16x16x32_bf16(af[rt], bfr[ct], acc[rt][ct], 0, 0, 0);
            __syncthreads();
        }

        // epilogue: 2 passes over ct; LDS rows = w*16+ln (64 l-rows), cols = k
#pragma unroll
        for (int ct = 0; ct < 2; ++ct) {
            const int lrow = w * 16 + ln;
#pragma unroll
            for (int rt = 0; rt < 4; ++rt) {
                unsigned pk[4];
#pragma unroll
                for (int reg = 0; reg < 4; ++reg) {
                    const int rloc = 16 * rt + quad * 4 + reg;
                    const float hm = acc[rt][ct][reg]     + bp[m0 + rloc];
                    const float hp = acc[rt + 4][ct][reg] + bp[m0 + 64 + rloc];
                    const float mag = fminf(__expf(hm), 100.0f);
                    pk[reg] = (unsigned)f2bf(mag * __cosf(hp)) |
                              ((unsigned)f2bf(mag * __sinf(hp)) << 16);
                }
                *(uint4*)&epi[lrow * 68 + 16 * rt + 4 * quad] = *(uint4*)pk;
            }
            __syncthreads();
            // reader: 1024 16B-chunks; chunk c -> lrow c>>4, kchunk c&15
#pragma unroll
            for (int i = 0; i < 4; ++i) {
                const int c = i * 256 + tid;
                const int row = c >> 4, kc = c & 15;
                if (kbase + kc * 4 < KP2U) {
                    const int l = l0 + 32 * (row >> 4) + 16 * ct + (row & 15);
                    uint4 v = *(const uint4*)&epi[row * 68 + kc * 4];
                    *(uint4*)&Sout[((size_t)bz * LEN + l) * KP2U + kbase + kc * 4] = v;
                }
            }
            __syncthreads();
        }
    }
}

// ---------------- OLA envelope (edges only; interior = 1.5 by COLA) ----------
__device__ __forceinline__ float env_at(int q, int s) {
    float env = 0.f;
#pragma unroll
    for (int r = 0; r < 4; ++r) {
        const int t = q - r;
        if (t >= 0 && t < LEN) {
            const float w = 0.5f - 0.5f * __cosf((float)(s + 256 * r) * (6.283185307179586f / 1024.f));
            env += w * w;
        }
    }
    return env;
}

// ---------------- GEMM2: y[256q+s-384] = sum_r sum_k D'[s,r,k] S[k, q-r] -----
// B-tile (132 S rows x 32 k) staged once per kk; A staged PER RSEG (8 KB live,
// double-buffered) -> block LDS 24.8 KB -> ~6 blocks/CU capacity.
// Epilogue: LDS transpose (stride 132 dwords) -> coalesced 512B y stores.
__global__ __launch_bounds__(256)
void gemm2_kernel(const unsigned short* __restrict__ D,   // 256 x 4224
                  const unsigned short* __restrict__ Sm,  // (bz*LEN + l)*1056 bf16
                  float* __restrict__ yout)
{
    __shared__ alignas(16) char smem[24832];
    unsigned short* Albuf = (unsigned short*)smem;           // 2 x 8192 B
    unsigned short* Blds  = (unsigned short*)(smem + 16384); // 8448 B
    float*          epi   = (float*)smem;                    // 32 x 132 f32 = 16896 B

    const int tid  = threadIdx.x;
    const int lane = tid & 63, w = tid >> 6;
    const int quad = lane >> 4, ln = lane & 15;
    const int sh = w >> 1, qh = w & 1;
    const int bx = blockIdx.x, by = blockIdx.y, bz = blockIdx.z;
    const int qt0 = bx * 128, s0 = by * 128;

    const size_t srowbase = (size_t)bz * LEN;
    const int ca0 = tid, ca1 = tid + 256;   // A chunks: row c>>2, kchunk c&3

    f32x4 acc[4][4];
#pragma unroll
    for (int a = 0; a < 4; ++a)
#pragma unroll
        for (int c = 0; c < 4; ++c) acc[a][c] = (f32x4){0.f, 0.f, 0.f, 0.f};

    for (int kk = 0; kk < KP2; kk += 32) {
        // ---- stage B: 132 rows x 32 cols, manual with OOB predication ----
        {
            const int r0 = ca0 >> 2, q0 = ca0 & 3, le0 = qt0 + r0 - 2;
            const int r1 = ca1 >> 2, q1 = ca1 & 3, le1 = qt0 + r1 - 2;
            uint4 v0 = {0, 0, 0, 0}, v1 = {0, 0, 0, 0};
            if ((unsigned)le0 < (unsigned)LEN)
                v0 = *(const uint4*)&Sm[(srowbase + le0) * KP2 + kk + q0 * 8];
            if ((unsigned)le1 < (unsigned)LEN)
                v1 = *(const uint4*)&Sm[(srowbase + le1) * KP2 + kk + q1 * 8];
            *(uint4*)&Blds[ca0 * 8] = v0;
            *(uint4*)&Blds[ca1 * 8] = v1;
            if (tid < 16) {
                const int c2 = 512 + tid;
                const int r2 = c2 >> 2, q2 = c2 & 3, le2 = qt0 + r2 - 2;
                uint4 v2 = {0, 0, 0, 0};
                if ((unsigned)le2 < (unsigned)LEN)
                    v2 = *(const uint4*)&Sm[(srowbase + le2) * KP2 + kk + q2 * 8];
                *(uint4*)&Blds[c2 * 8] = v2;
            }
        }
        // ---- stage A rseg 0 into buf 0 ----
        gld16(D + (size_t)(s0 + (ca0 >> 2)) * K2 + kk + (ca0 & 3) * 8, &Albuf[ca0 * 8]);
        gld16(D + (size_t)(s0 + (ca1 >> 2)) * K2 + kk + (ca1 & 3) * 8, &Albuf[ca1 * 8]);
        __syncthreads();

#pragma unroll
        for (int rseg = 0; rseg < 4; ++rseg) {
            const int buf = rseg & 1;
            if (rseg < 3) {   // prefetch next rseg into other buffer
                const unsigned short* src = D + (rseg + 1) * KP2 + kk;
                gld16(src + (size_t)(s0 + (ca0 >> 2)) * K2 + (ca0 & 3) * 8,
                      &Albuf[(buf ^ 1) * 4096 + ca0 * 8]);
                gld16(src + (size_t)(s0 + (ca1 >> 2)) * K2 + (ca1 & 3) * 8,
                      &Albuf[(buf ^ 1) * 4096 + ca1 * 8]);
            }
            short8 af[4], bfr[4];
#pragma unroll
            for (int rt = 0; rt < 4; ++rt)
                af[rt] = *(const short8*)&Albuf[buf * 4096 + ((64 * sh + 16 * rt + ln) * 4 + quad) * 8];
#pragma unroll
            for (int ct = 0; ct < 4; ++ct)
                bfr[ct] = *(const short8*)&Blds[((3 - rseg + 64 * qh + 16 * ct + ln) * 4 + quad) * 8];
#pragma unroll
            for (int rt = 0; rt < 4; ++rt)
#pragma unroll
                for (int ct = 0; ct < 4; ++ct)
                    acc[rt][ct] = __builtin_amdgcn_mfma_f32_16x16x32_bf16(af[rt], bfr[ct], acc[rt][ct], 0, 0, 0);
            __syncthreads();
        }
    }

    // ---- epilogue: 4 passes over ct; LDS rows = qh*16+ln (32 qi), cols = s ----
    float* yb = yout + (size_t)bz * OUTL;
#pragma unroll
    for (int ct = 0; ct < 4; ++ct) {
        const int qrow = qh * 16 + ln;
#pragma unroll
        for (int rt = 0; rt < 4; ++rt)
            *(f32x4*)&epi[qrow * 132 + 64 * sh + 16 * rt + 4 * quad] = acc[rt][ct];
        __syncthreads();
        // reader: 1024 16B-chunks; chunk c -> qrow c>>5, s-chunk c&31
#pragma unroll
        for (int i = 0; i < 4; ++i) {
            const int c = i * 256 + tid;
            const int row = c >> 5, sc = c & 31;
            const int qi = qt0 + 64 * (row >> 4) + 16 * ct + (row & 15);
            const int q = qi + 1;
            const int j = 256 * qi + (s0 + sc * 4) - 128;
            if ((unsigned)j < (unsigned)(OUTL - 3)) {
                f32x4 v = *(const f32x4*)&epi[row * 132 + sc * 4];
                if (q >= 3 && q <= 4095) {
                    v *= (2.0f / 3.0f);
                } else {
#pragma unroll
                    for (int e = 0; e < 4; ++e)
                        v[e] /= env_at(q, s0 + sc * 4 + e);
                }
                *(f32x4*)&yb[j] = v;
            }
        }
        __syncthreads();
    }
}

// ---------------- launch -----------------------------------------------------
// Workspace layout (~209 MB):
//   xT  : 16*4096*512  bf16  =  67,108,864 B   @ 0
//   Wb  : 1152*512     bf16  =   1,179,648 B   @ 67,108,864
//   bp  : 1152         f32   =       4,608 B   @ 68,288,512
//   D'  : 256*4224     bf16  =   2,162,688 B   @ 68,293,120
//   S   : 16*4096*528  u32   = 138,412,032 B   @ 70,455,808
extern "C" void kernel_launch(void* const* d_in, const int* in_sizes, int n_in,
                              void* d_out, int out_size, void* d_ws, size_t ws_size,
                              hipStream_t stream) {
    const float* x    = (const float*)d_in[0];
    const float* W    = (const float*)d_in[1];
    const float* bvec = (const float*)d_in[2];
    float* y = (float*)d_out;
    char* ws = (char*)d_ws;

    unsigned short* xT = (unsigned short*)(ws);
    unsigned short* Wb = (unsigned short*)(ws + 67108864);
    float*          bp = (float*)(ws + 68288512);
    unsigned short* D  = (unsigned short*)(ws + 68293120);
    unsigned*       S  = (unsigned*)(ws + 70455808);

    transpose_x<<<dim3(128, 16, BATCH), dim3(32, 8), 0, stream>>>(x, xT);
    pack_W<<<dim3(1152), dim3(256), 0, stream>>>(W, bvec, Wb, bp);
    build_D<<<dim3((256 * K2 + 255) / 256), dim3(256), 0, stream>>>(D);

    // GEMM1: 3 m-tiles per block for guaranteed B-tile L2 reuse
    gemm1_kernel<<<dim3(32, 3, BATCH), dim3(256), 0, stream>>>(Wb, xT, bp, S);

    // GEMM2: gather-OLA GEMM, rseg-sequential A staging, coalesced epilogue
    gemm2_kernel<<<dim3(33, 2, BATCH), dim3(256), 0, stream>>>(
        D, (const unsigned short*)S, y);
}